// Round 13
// baseline (1040.369 us; speedup 1.0000x reference)
//
#include <hip/hip_runtime.h>
#include <math.h>

#define H 128
typedef unsigned short u16;
typedef unsigned char u8;
typedef unsigned int u32;
typedef _Float16 f16;
typedef f16 f16x8 __attribute__((ext_vector_type(8)));
typedef float f32x4 __attribute__((ext_vector_type(4)));
typedef float f32x2 __attribute__((ext_vector_type(2)));

typedef __attribute__((address_space(1))) const void gas_void;
typedef __attribute__((address_space(3))) void las_void;

#if __has_builtin(__builtin_amdgcn_cvt_pk_fp8_f32)
#define HW8 1
#else
#define HW8 0
#endif

#define SSTRIDE 144   // fp8 staging row stride
#define STGW 9216     // per-wave: 4x2048 feat ring + 1024 nbr window

static inline int cdiv(long long a, long long b) { return (int)((a + b - 1) / b); }

// Per-segment XCD-chunked swizzle (balanced: 1/8 of node + 1/8 of line per XCD).
__device__ __forceinline__ int swz_seg(int orig, int n) {
    int q = n >> 3, r = n & 7;
    int x = orig & 7;
    int base = (x < r) ? x * (q + 1) : r * (q + 1) + (x - r) * q;
    return base + (orig >> 3);
}
__device__ __forceinline__ int conv_bid(int orig, int nbCN, int nwg) {
    return (orig < nbCN) ? swz_seg(orig, nbCN)
                         : nbCN + swz_seg(orig - nbCN, nwg - nbCN);
}

// ---------------- fp8 e4m3fn software codec (fallback) ----------------
struct F8 {
    static __device__ inline float dec(u8 v) {
        int e = (v >> 3) & 15, m = v & 7;
        float f = (e == 0) ? (float)m * 0.001953125f : ldexpf(1.f + 0.125f * (float)m, e - 7);
        return (v & 0x80) ? -f : f;
    }
    static __device__ inline u8 enc(float x) {
        u8 s = (u8)((__float_as_uint(x) >> 24) & 0x80);
        float ax = fabsf(x);
        if (!(ax < 448.f)) return s | 0x7E;
        if (ax < 0.015625f) {
            int m = (int)rintf(ax * 512.f);
            if (m >= 8) return s | 0x08;
            return s | (u8)m;
        }
        int e; float fr = frexpf(ax, &e);
        int E = e - 1;
        int m = (int)rintf(fr * 16.f - 8.f);
        if (m == 8) { m = 0; ++E; }
        if (E > 8) return s | 0x7E;
        return s | (u8)(((E + 7) << 3) | m);
    }
};

static __device__ inline u32 enc4(float x0, float x1, float x2, float x3) {
#if HW8
    u32 w = __builtin_amdgcn_cvt_pk_fp8_f32(x0, x1, 0, false);
    w = __builtin_amdgcn_cvt_pk_fp8_f32(x2, x3, w, true);
    return w;
#else
    union { u8 b[4]; u32 u; } p;
    p.b[0] = F8::enc(x0); p.b[1] = F8::enc(x1); p.b[2] = F8::enc(x2); p.b[3] = F8::enc(x3);
    return p.u;
#endif
}
static __device__ inline float4 dec4(u32 v) {
#if HW8
    f32x2 lo = __builtin_amdgcn_cvt_pk_f32_fp8(v, false);
    f32x2 hi = __builtin_amdgcn_cvt_pk_f32_fp8(v, true);
    return make_float4(lo.x, lo.y, hi.x, hi.y);
#else
    union { u32 u; u8 b[4]; } c; c.u = v;
    return make_float4(F8::dec(c.b[0]), F8::dec(c.b[1]), F8::dec(c.b[2]), F8::dec(c.b[3]));
#endif
}

// ---------------- setup1: prep_w ++ hist_all ++ seg2 ++ uv precompute, one dispatch ----------------
__global__ __launch_bounds__(256) void setup1_k(
    const float* __restrict__ gW, const float* __restrict__ lgW, f16* __restrict__ wt, int L, int nbPW,
    const int* __restrict__ src, const int* __restrict__ dst,
    const int* __restrict__ lsrc, const int* __restrict__ ldst,
    int* __restrict__ con, int* __restrict__ cin, int* __restrict__ coe, int* __restrict__ cie,
    int E, int E2, int nbHI,
    const int* __restrict__ node_graph, int N, const int* __restrict__ edge_graph,
    int B, int* __restrict__ cntn, int* __restrict__ cnte,
    const float* __restrict__ epw, const float* __restrict__ epb, float* __restrict__ uv) {
    int blk = blockIdx.x;
    if (blk < nbPW) {                       // weight prep
        int mat = blk >> 6;
        int idx = (blk & 63) * 256 + threadIdx.x;
        int k = idx >> 7, n = idx & 127;
        const float* W = (mat < L) ? gW + (size_t)mat * H * H : lgW + (size_t)(mat - L) * H * H;
        wt[(size_t)mat * H * H + (size_t)n * H + k] = (f16)W[(size_t)k * H + n];
        return;
    }
    blk -= nbPW;
    if (blk < nbHI) {                       // degree histograms
        int i = blk * 256 + threadIdx.x;
        if (i < E) {
            atomicAdd(&con[src[i]], 1);
            atomicAdd(&cin[dst[i]], 1);
        } else if (i < E + E2) {
            int j = i - E;
            atomicAdd(&coe[lsrc[j]], 1);
            atomicAdd(&cie[ldst[j]], 1);
        }
        return;
    }
    blk -= nbHI;                            // seg bounds (2 blocks)
    if (blk < 2) {
        const int* seg = blk ? edge_graph : node_graph;
        int n = blk ? E : N;
        int* cnt = blk ? cnte : cntn;
        __shared__ int bound[129];
        int b = threadIdx.x;
        if (b <= B) {
            int lo = 0, hi = n;
            while (lo < hi) {
                int mid = (lo + hi) >> 1;
                if (seg[mid] < b) lo = mid + 1; else hi = mid;
            }
            bound[b] = lo;
        }
        __syncthreads();
        if (b < B) cnt[b] = bound[b + 1] - bound[b];
        return;
    }
    // last block: uv precompute  u = epw @ lgW[0],  v = epb @ lgW[0]
    {
        int n = threadIdx.x;
        if (n < H) {
            float su = 0.f, sv = 0.f;
            for (int k = 0; k < H; ++k) {
                float w = lgW[(size_t)k * H + n];
                su = fmaf(epw[k], w, su);
                sv = fmaf(epb[k], w, sv);
            }
            uv[n] = su;
            uv[n + H] = sv;
        }
    }
}

// ---------------- setup2: rs_all(+pairE) ++ scan_block2, one dispatch ----------------
__global__ __launch_bounds__(256) void setup2_k(
    const int* __restrict__ con, const int* __restrict__ cin,
    const int* __restrict__ coe, const int* __restrict__ cie,
    float* __restrict__ ron, float* __restrict__ rin,
    float* __restrict__ roe, float* __restrict__ rie,
    const float* __restrict__ d, float2* __restrict__ pairE, int N, int E, int nbRS,
    int* __restrict__ offs_n, int nbN, int* __restrict__ offs_e, int* __restrict__ bsum) {
    int blk = blockIdx.x;
    if (blk < nbRS) {                       // rs + pairE
        int i = blk * 256 + threadIdx.x;
        if (i < N) { int v = con[i]; ron[i] = rsqrtf((float)(v < 1 ? 1 : v)); }
        else if (i < 2 * N) { int n = i - N; int v = cin[n]; rin[n] = rsqrtf((float)(v < 1 ? 1 : v)); }
        else if (i < 2 * N + E) {
            int n = i - 2 * N; int v = coe[n];
            float r = rsqrtf((float)(v < 1 ? 1 : v));
            roe[n] = r;
            pairE[n] = make_float2(r * d[n], r);
        } else if (i < 2 * N + 2 * E) {
            int n = i - 2 * N - E; int v = cie[n]; rie[n] = rsqrtf((float)(v < 1 ? 1 : v));
        }
        return;
    }
    blk -= nbRS;                            // block scans (nbN for cin->offs_n, rest cie->offs_e)
    {
        __shared__ int sh[256];
        const int* in; int* out; int n; int gid;
        if (blk < nbN) { in = cin; out = offs_n; n = N; gid = blk * 256 + threadIdx.x; }
        else { in = cie; out = offs_e; n = E; gid = (blk - nbN) * 256 + threadIdx.x; }
        int v = (gid < n) ? in[gid] : 0;
        sh[threadIdx.x] = v;
        __syncthreads();
        for (int off = 1; off < 256; off <<= 1) {
            int t = (threadIdx.x >= off) ? sh[threadIdx.x - off] : 0;
            __syncthreads();
            sh[threadIdx.x] += t;
            __syncthreads();
        }
        if (gid < n) out[gid] = sh[threadIdx.x] - v;
        if (threadIdx.x == 255) bsum[blk] = sh[255];
    }
}

__global__ __launch_bounds__(256) void scan_bsum2_k(int* __restrict__ bsum, int nbA, int nbB) {
    __shared__ int sh[256];
    __shared__ int carry;
#pragma unroll 1
    for (int part = 0; part < 2; ++part) {
        int base0 = part ? nbA : 0;
        int nb = part ? nbB : nbA;
        if (threadIdx.x == 0) carry = 0;
        __syncthreads();
        for (int base = 0; base < nb; base += 256) {
            int i = base + threadIdx.x;
            int v = (i < nb) ? bsum[base0 + i] : 0;
            sh[threadIdx.x] = v;
            __syncthreads();
            for (int off = 1; off < 256; off <<= 1) {
                int t = (threadIdx.x >= off) ? sh[threadIdx.x - off] : 0;
                __syncthreads();
                sh[threadIdx.x] += t;
                __syncthreads();
            }
            if (i < nb) bsum[base0 + i] = sh[threadIdx.x] - v + carry;
            __syncthreads();
            if (threadIdx.x == 0) carry += sh[255];
            __syncthreads();
        }
    }
}

// ---------------- setup3: scan_add2 ++ init_node, one dispatch ----------------
__global__ __launch_bounds__(256) void setup3_k(
    int* __restrict__ offs_n, int* __restrict__ cur_n, int N, int nbN, int E,
    int* __restrict__ offs_e, int* __restrict__ cur_e, int E2, int nbE,
    const int* __restrict__ bsum,
    const int* __restrict__ z, const float* __restrict__ emb,
    const float* __restrict__ ron, u8* __restrict__ featN) {
    int blk = blockIdx.x;
    int nbSA = nbN + nbE;
    if (blk < nbSA) {                       // scan add (offs += bsum; cursor init; tail nnz)
        int* offs; int* curp; int n; int gid; int nnz;
        if (blk < nbN) { offs = offs_n; curp = cur_n; n = N; gid = blk * 256 + threadIdx.x; nnz = E; }
        else { offs = offs_e; curp = cur_e; n = E; gid = (blk - nbN) * 256 + threadIdx.x; nnz = E2; }
        if (gid < n) {
            int v = offs[gid] + bsum[blk];
            offs[gid] = v;
            curp[gid] = v;
        }
        if (gid == 0) offs[n] = nnz;
        return;
    }
    blk -= nbSA;                            // node feature init (fp8, pre-scaled by ron)
    {
        int idx = blk * 256 + threadIdx.x;
        if (idx >= N * 32) return;
        int n = idx >> 5, c4 = (idx & 31) << 2;
        float sc = ron[n];
        const float4 v = *(const float4*)(emb + (size_t)z[n] * H + c4);
        *(u32*)(featN + (size_t)n * H + c4) = enc4(v.x * sc, v.y * sc, v.z * sc, v.w * sc);
    }
}

// ---------------- CSR fill (both graphs): slot gets (src, dst) pair; line slots also pairE ----------------
__global__ __launch_bounds__(256) void fill2_k(const int* __restrict__ src, const int* __restrict__ dst,
                                               const int* __restrict__ lsrc, const int* __restrict__ ldst,
                                               int* __restrict__ cur_n, int* __restrict__ cur_e,
                                               uint2* __restrict__ nbr_n, uint2* __restrict__ nbr_e,
                                               const float2* __restrict__ pairE, float2* __restrict__ pslot,
                                               int E, int E2) {
    int i = blockIdx.x * 256 + threadIdx.x;
    if (i < E) {
        int dd = dst[i];
        int p = atomicAdd(&cur_n[dd], 1);
        nbr_n[p] = make_uint2((u32)src[i], (u32)dd);
    } else if (i < E + E2) {
        int j = i - E;
        int ls = lsrc[j];
        int dd = ldst[j];
        int p = atomicAdd(&cur_e[dd], 1);
        nbr_e[p] = make_uint2((u32)ls, (u32)dd);
        pslot[p] = pairE[ls];               // CSR-ordered copy: l0 gather becomes sequential
    }
}

// ---------------- gather: ALL-LDS pipeline -- nbr chunk DMA + feature ring-4, vmcnt(6) ----------------
// r12 lesson: register e-loads inside the loop force the compiler to insert a
// conservative waitcnt before STAGE consumes them, draining the ring every
// iteration (per-batch ~650cy, matching r9/r12). Here the steady loop has NO
// register VMEM loads: nbr entries are DMA'd to LDS once per 32-edge chunk
// (drain once, amortized), then x/y values come from LDS (lgkmcnt -- separate
// counter, never drains vmcnt). Feature ring is 4-deep, staged 3 batches
// ahead, gated by asm vmcnt(6) -- counted, never 0 in the loop.
__device__ __forceinline__ void gather_phase(
    const u8* __restrict__ Xin,
    const int* __restrict__ offs, const uint2* __restrict__ nbr2,
    const float* __restrict__ rs_in, int M,
    int row0, f16 (*As)[136], u8* __restrict__ stgW, int wave, int lane) {
    const int rowbase = row0 + wave * 16;
    {
        uint2* zp = (uint2*)&As[wave * 16][0];
#pragma unroll
        for (int i = 0; i < 9; ++i) {
            int o = lane + i * 64;
            if (o < 544) zp[o] = make_uint2(0u, 0u);
        }
    }
    const int gl = lane >> 4;
    const int ln = lane & 15;
    const int rbase4 = rowbase + gl * 4;
    const int jbeg = offs[min(rbase4, M)];
    const int jend = offs[min(rbase4 + 4, M)];
    if (jbeg >= jend) return;
    const int mrow = M - 1;
    const float rsr0 = rs_in[min(rbase4 + 0, mrow)];
    const float rsr1 = rs_in[min(rbase4 + 1, mrow)];
    const float rsr2 = rs_in[min(rbase4 + 2, mrow)];
    const float rsr3 = rs_in[min(rbase4 + 3, mrow)];

    float a0 = 0.f, a1 = 0.f, a2 = 0.f, a3 = 0.f, a4 = 0.f, a5 = 0.f, a6 = 0.f, a7 = 0.f;
    int curdst = -1;

#define FLUSH_ROW()                                                              \
    do {                                                                         \
        const int dd_ = curdst - rbase4;                                         \
        const float ri_ = dd_ == 0 ? rsr0 : (dd_ == 1 ? rsr1 : (dd_ == 2 ? rsr2 : rsr3)); \
        f16x8 o_;                                                                \
        o_[0] = (f16)(a0 * ri_); o_[1] = (f16)(a1 * ri_);                        \
        o_[2] = (f16)(a2 * ri_); o_[3] = (f16)(a3 * ri_);                        \
        o_[4] = (f16)(a4 * ri_); o_[5] = (f16)(a5 * ri_);                        \
        o_[6] = (f16)(a6 * ri_); o_[7] = (f16)(a7 * ri_);                        \
        *(f16x8*)&As[curdst - row0][ln << 3] = o_;                               \
    } while (0)

    u8* featRing = stgW;              // 4 x 2048
    u8* nbrW = stgW + 8192;           // 1024: group gl at gl*256; entry j at j*8 (x,y)
    const int sub = (lane >> 3) & 1;
    const size_t c16 = (size_t)(lane & 7) << 4;

    // Stage batch at chunk position bb (0..7): x-pair from LDS, min-clamped so
    // clamped/garbage tail entries still give in-bounds row addresses.
#define STAGE_B(bb, rg) do {                                                     \
        u32 xa_ = *(const u32*)(nbrW + gl * 256 + ((((bb) << 2) + sub) & 31) * 8);       \
        u32 xb_ = *(const u32*)(nbrW + gl * 256 + ((((bb) << 2) + 2 + sub) & 31) * 8);   \
        xa_ = min(xa_, (u32)mrow); xb_ = min(xb_, (u32)mrow);                    \
        __builtin_amdgcn_global_load_lds(                                        \
            (gas_void*)(Xin + ((size_t)xa_ << 7) + c16),                         \
            (las_void*)(featRing + (rg) * 2048), 16, 0, 0);                      \
        __builtin_amdgcn_global_load_lds(                                        \
            (gas_void*)(Xin + ((size_t)xb_ << 7) + c16),                         \
            (las_void*)(featRing + (rg) * 2048 + 1024), 16, 0, 0);               \
    } while (0)

    for (int cb = jbeg; cb < jend; cb += 32) {
        {   // nbr chunk DMA: lane ln covers group entries 2*ln, 2*ln+1 (clamped)
            int ce = min(cb + 2 * ln, jend - 1);
            __builtin_amdgcn_global_load_lds((gas_void*)(nbr2 + ce),
                                             (las_void*)nbrW, 16, 0, 0);
        }
        asm volatile("s_waitcnt vmcnt(0)" ::: "memory");   // once per chunk (<=8 batches)
        __builtin_amdgcn_sched_barrier(0);
        const int nbat = min((jend - cb + 3) >> 2, 8);
        // prologue: fill ring 3 deep (clamped batch ids; redundant stages harmless)
        STAGE_B(0, 0);
        STAGE_B(min(1, nbat - 1), 1);
        STAGE_B(min(2, nbat - 1), 2);
        for (int b = 0; b < nbat; ++b) {
            STAGE_B(min(b + 3, nbat - 1), (b + 3) & 3);
            asm volatile("s_waitcnt vmcnt(6)" ::: "memory");   // ring[b] resident; 3 ahead in flight
            __builtin_amdgcn_sched_barrier(0);
            const u8* fb = featRing + (b & 3) * 2048 + gl * 256;
            const u8* yb = nbrW + gl * 256 + (b << 5);
#pragma unroll
            for (int k = 0; k < 4; ++k) {
                if (cb + (b << 2) + k < jend) {
                    const int dk = *(const int*)(yb + k * 8 + 4);
                    if (dk != curdst) {
                        if (curdst >= 0) {
                            FLUSH_ROW();
                            a0 = a1 = a2 = a3 = a4 = a5 = a6 = a7 = 0.f;
                        }
                        curdst = dk;
                    }
                    uint2 fv = *(const uint2*)(fb + (k >> 1) * 1024 + (k & 1) * 128 + (ln << 3));
                    float4 lo = dec4(fv.x);
                    float4 hi = dec4(fv.y);
                    a0 += lo.x; a1 += lo.y; a2 += lo.z; a3 += lo.w;
                    a4 += hi.x; a5 += hi.y; a6 += hi.z; a7 += hi.w;
                }
            }
        }
    }
    FLUSH_ROW();
#undef STAGE_B
#undef FLUSH_ROW
}

// ---------------- MFMA phase: LDS-staged fp8 output; optional full-line global store ----------------
template <bool STORE>
__device__ __forceinline__ void conv_mfma_phase(
    u8* __restrict__ Xout, const f16* __restrict__ Wt, const float* __restrict__ bias,
    const float* __restrict__ scale_out, int M, int row0, f16 (*As)[136], int wave, int lane) {
    const int rowbase = row0 + wave * 16;
    if (rowbase >= M) return;
    const int l15 = lane & 15;
    const int quad = lane >> 4;

    f16x8 a[4];
#pragma unroll
    for (int kt = 0; kt < 4; ++kt)
        a[kt] = *(const f16x8*)&As[wave * 16 + l15][kt * 32 + quad * 8];

    float rsc[4];
#pragma unroll
    for (int r = 0; r < 4; ++r) {
        int gr = rowbase + quad * 4 + r;
        rsc[r] = (scale_out && gr < M) ? scale_out[gr] : 1.f;
    }

    u8* stage = (u8*)&As[wave * 16][0];

#pragma unroll
    for (int n0 = 0; n0 < 8; ++n0) {
        f32x4 acc = {0.f, 0.f, 0.f, 0.f};
        const f16* bp = Wt + (size_t)(n0 * 16 + l15) * H + quad * 8;
#pragma unroll
        for (int kt = 0; kt < 4; ++kt) {
            f16x8 b = *(const f16x8*)(bp + kt * 32);
            acc = __builtin_amdgcn_mfma_f32_16x16x32_f16(a[kt], b, acc, 0, 0, 0);
        }
        int col = n0 * 16 + l15;
        float bv = bias[col];
        float o[4];
#pragma unroll
        for (int r = 0; r < 4; ++r) o[r] = fmaxf(acc[r] + bv, 0.f) * rsc[r];
        u32 w = enc4(o[0], o[1], o[2], o[3]);
#pragma unroll
        for (int r = 0; r < 4; ++r) stage[(quad * 4 + r) * SSTRIDE + col] = (u8)(w >> (8 * r));
    }
    if (STORE) {
        const int lr = lane >> 2;
        const int lc = (lane & 3) * 32;
        int gr = rowbase + lr;
        if (gr < M) {
            uint4 v0 = *(const uint4*)&stage[lr * SSTRIDE + lc];
            uint4 v1 = *(const uint4*)&stage[lr * SSTRIDE + lc + 16];
            *(uint4*)(Xout + (size_t)gr * H + lc) = v0;
            *(uint4*)(Xout + (size_t)gr * H + lc + 16) = v1;
        }
    }
}

// ---------------- MFMA + register-space pooling (last layer; no fp8 stage) ----------------
__device__ __forceinline__ void conv_mfma_pool_phase(
    const f16* __restrict__ Wt, const float* __restrict__ bias, int M, int row0,
    f16 (*As)[136], float (*pool)[128], int wave, int lane,
    const int* __restrict__ seg, float* __restrict__ outp, bool uni) {
    const int rowbase = row0 + wave * 16;
    if (rowbase >= M) return;       // pool[wave] stays zeroed
    const int l15 = lane & 15;
    const int quad = lane >> 4;

    f16x8 a[4];
#pragma unroll
    for (int kt = 0; kt < 4; ++kt)
        a[kt] = *(const f16x8*)&As[wave * 16 + l15][kt * 32 + quad * 8];

    const int gr0 = rowbase + quad * 4;
    const int remM = M - gr0;       // rows valid iff r < remM
    int g0 = -1, g1 = -1, g2 = -1, g3 = -1;
    if (!uni) {                     // block-uniform branch
        g0 = (0 < remM) ? seg[gr0 + 0] : -1;
        g1 = (1 < remM) ? seg[gr0 + 1] : -1;
        g2 = (2 < remM) ? seg[gr0 + 2] : -1;
        g3 = (3 < remM) ? seg[gr0 + 3] : -1;
    }

#pragma unroll
    for (int n0 = 0; n0 < 8; ++n0) {
        f32x4 acc = {0.f, 0.f, 0.f, 0.f};
        const f16* bp = Wt + (size_t)(n0 * 16 + l15) * H + quad * 8;
#pragma unroll
        for (int kt = 0; kt < 4; ++kt) {
            f16x8 b = *(const f16x8*)(bp + kt * 32);
            acc = __builtin_amdgcn_mfma_f32_16x16x32_f16(a[kt], b, acc, 0, 0, 0);
        }
        const int col = n0 * 16 + l15;
        const float bv = bias[col];
        const float o0 = (0 < remM) ? fmaxf(acc[0] + bv, 0.f) : 0.f;
        const float o1 = (1 < remM) ? fmaxf(acc[1] + bv, 0.f) : 0.f;
        const float o2 = (2 < remM) ? fmaxf(acc[2] + bv, 0.f) : 0.f;
        const float o3 = (3 < remM) ? fmaxf(acc[3] + bv, 0.f) : 0.f;
        if (uni) {
            float s = (o0 + o1) + (o2 + o3);
            s += __shfl_xor(s, 16);
            s += __shfl_xor(s, 32);
            if (quad == 0) pool[wave][col] = s;   // cols unique per wave: plain store
        } else {
            // rare boundary block: per-lane run-flush to global
            float ac = o0; int gc = g0;
            if (g1 == gc) ac += o1; else { if (gc >= 0) atomicAdd(&outp[(size_t)gc * H + col], ac); gc = g1; ac = o1; }
            if (g2 == gc) ac += o2; else { if (gc >= 0) atomicAdd(&outp[(size_t)gc * H + col], ac); gc = g2; ac = o2; }
            if (g3 == gc) ac += o3; else { if (gc >= 0) atomicAdd(&outp[(size_t)gc * H + col], ac); gc = g3; ac = o3; }
            if (gc >= 0) atomicAdd(&outp[(size_t)gc * H + col], ac);
        }
    }
}

template <bool STORE>
__device__ __forceinline__ void conv_wave(
    const u8* __restrict__ Xin, u8* __restrict__ Xout,
    const int* __restrict__ offs, const uint2* __restrict__ nbr2,
    const float* __restrict__ rs_in, const f16* __restrict__ Wt,
    const float* __restrict__ bias, const float* __restrict__ scale_out, int M,
    int row0, f16 (*As)[136], u8* __restrict__ stgW, int wave, int lane) {
    gather_phase(Xin, offs, nbr2, rs_in, M, row0, As, stgW, wave, lane);
    // no __syncthreads: As slice + staging are wave-private
    conv_mfma_phase<STORE>(Xout, Wt, bias, scale_out, M, row0, As, wave, lane);
}

// ---------------- layer-0 line conv wave: rank-2 algebraic collapse, no LDS/MFMA ----------------
// e_row = sd*epw + sw*epb  =>  out = relu(sd*(epw@W) + sw*(epb@W) + b) * scale
__device__ __forceinline__ void conv_wave_l0e(
    u8* __restrict__ Xout, const int* __restrict__ offs,
    const float2* __restrict__ pslot, const float* __restrict__ rs_in,
    const float* __restrict__ uv, const float* __restrict__ bias,
    const float* __restrict__ scale_out, int E,
    int row0, int wave, int lane) {
    const int rowbase = row0 + wave * 16;
    const int r = lane >> 2;
    const int t = lane & 3;
    const int growu = rowbase + r;
    const int grow = min(growu, E - 1);
    const int jb = offs[grow];
    const int je = offs[grow + 1];
    float sd = 0.f, sw = 0.f;
    for (int j = jb + t; j < je; j += 4) {
        float2 p = pslot[j];                 // sequential in CSR order: 1-level chain
        sd += p.x; sw += p.y;
    }
    sd += __shfl_xor(sd, 1); sw += __shfl_xor(sw, 1);
    sd += __shfl_xor(sd, 2); sw += __shfl_xor(sw, 2);
    if (growu >= E) return;
    const float ri = rs_in[growu];
    const float so = scale_out[growu];
    sd *= ri; sw *= ri;
    const int c0 = t * 32;
    u32 wbuf[8];
#pragma unroll
    for (int c4 = 0; c4 < 8; ++c4) {
        const int c = c0 + c4 * 4;
        const float4 ua = *(const float4*)(uv + c);
        const float4 va = *(const float4*)(uv + H + c);
        const float4 ba = *(const float4*)(bias + c);
        const float o0 = fmaxf(fmaf(sd, ua.x, fmaf(sw, va.x, ba.x)), 0.f) * so;
        const float o1 = fmaxf(fmaf(sd, ua.y, fmaf(sw, va.y, ba.y)), 0.f) * so;
        const float o2 = fmaxf(fmaf(sd, ua.z, fmaf(sw, va.z, ba.z)), 0.f) * so;
        const float o3 = fmaxf(fmaf(sd, ua.w, fmaf(sw, va.w, ba.w)), 0.f) * so;
        wbuf[c4] = enc4(o0, o1, o2, o3);
    }
    *(uint4*)(Xout + (size_t)growu * H + c0) = *(uint4*)&wbuf[0];
    *(uint4*)(Xout + (size_t)growu * H + c0 + 16) = *(uint4*)&wbuf[4];
}

// ---------------- combined conv (middle layer): 128t/2-wave blocks + all-LDS pipeline ----------------
// (128, 4): budget 64 (256-reg-pool model, measured r7-r9). LDS/block = As 8704
// + 2 x STGW 9216 = 27136 -> 4 blocks/CU fits 160KB pool.
__global__ __launch_bounds__(128, 4) void conv2_k(
    const u8* __restrict__ XinN, u8* __restrict__ XoutN,
    const int* __restrict__ offs_n, const uint2* __restrict__ nbr_n,
    const float* __restrict__ rinN, const f16* __restrict__ WtN,
    const float* __restrict__ biasN, const float* __restrict__ scaleN, int N, int nbCN,
    const u8* __restrict__ XinE, u8* __restrict__ XoutE,
    const int* __restrict__ offs_e, const uint2* __restrict__ nbr_e,
    const float* __restrict__ rinE, const f16* __restrict__ WtE,
    const float* __restrict__ biasE, const float* __restrict__ scaleE, int E) {
    __shared__ f16 As[32][136];
    __shared__ u8 Stg[2][STGW];
    const int tid = threadIdx.x;
    const int wave = tid >> 6;
    const int lane = tid & 63;
    const int bid = conv_bid((int)blockIdx.x, nbCN, (int)gridDim.x);
    if (bid < nbCN) {
        conv_wave<true>(XinN, XoutN, offs_n, nbr_n, rinN, WtN, biasN, scaleN, N,
                        bid * 32, As, Stg[wave], wave, lane);
    } else {
        conv_wave<true>(XinE, XoutE, offs_e, nbr_e, rinE, WtE, biasE, scaleE, E,
                        (bid - nbCN) * 32, As, Stg[wave], wave, lane);
    }
}

// ---------------- combined conv layer 0: node standard ++ line rank-2 collapse ----------------
__global__ __launch_bounds__(128, 4) void conv2_l0_k(
    const u8* __restrict__ XinN, u8* __restrict__ XoutN,
    const int* __restrict__ offs_n, const uint2* __restrict__ nbr_n,
    const float* __restrict__ rinN, const f16* __restrict__ WtN,
    const float* __restrict__ biasN, const float* __restrict__ scaleN, int N, int nbCN,
    u8* __restrict__ XoutE,
    const int* __restrict__ offs_e, const float2* __restrict__ pslot,
    const float* __restrict__ rinE, const float* __restrict__ uv,
    const float* __restrict__ biasE, const float* __restrict__ scaleE, int E) {
    __shared__ f16 As[32][136];
    __shared__ u8 Stg[2][STGW];
    const int tid = threadIdx.x;
    const int wave = tid >> 6;
    const int lane = tid & 63;
    const int bid = conv_bid((int)blockIdx.x, nbCN, (int)gridDim.x);
    if (bid < nbCN) {
        conv_wave<true>(XinN, XoutN, offs_n, nbr_n, rinN, WtN, biasN, scaleN, N,
                        bid * 32, As, Stg[wave], wave, lane);
    } else {
        conv_wave_l0e(XoutE, offs_e, pslot, rinE, uv, biasE, scaleE, E,
                      (bid - nbCN) * 32, wave, lane);
    }
}

// ---------------- final conv layer: conv + register-space fused block pooling (32 rows) ----------------
__global__ __launch_bounds__(128, 4) void conv2_last_k(
    const u8* __restrict__ XinN,
    const int* __restrict__ offs_n, const uint2* __restrict__ nbr_n,
    const float* __restrict__ rinN, const f16* __restrict__ WtN,
    const float* __restrict__ biasN, int N, int nbCN,
    const int* __restrict__ node_graph, float* __restrict__ hg,
    const u8* __restrict__ XinE,
    const int* __restrict__ offs_e, const uint2* __restrict__ nbr_e,
    const float* __restrict__ rinE, const f16* __restrict__ WtE,
    const float* __restrict__ biasE, int E,
    const int* __restrict__ edge_graph, float* __restrict__ he) {
    __shared__ f16 As[32][136];
    __shared__ u8 Stg[2][STGW];
    __shared__ float pool[2][128];
    const int tid = threadIdx.x;
    const int wave = tid >> 6;
    const int lane = tid & 63;
    const int bid = conv_bid((int)blockIdx.x, nbCN, (int)gridDim.x);
    const bool isN = bid < nbCN;
    const int row0 = (isN ? bid : bid - nbCN) * 32;
    const int M = isN ? N : E;
    const int* seg = isN ? node_graph : edge_graph;
    float* outp = isN ? hg : he;

    ((float*)pool)[tid] = 0.f;
    ((float*)pool)[tid + 128] = 0.f;
    const int gblk = seg[row0];
    const bool uni = (seg[min(row0 + 31, M - 1)] == gblk);
    __syncthreads();

    if (isN) {
        gather_phase(XinN, offs_n, nbr_n, rinN, N, row0, As, Stg[wave], wave, lane);
        conv_mfma_pool_phase(WtN, biasN, N, row0, As, pool, wave, lane, seg, outp, uni);
    } else {
        gather_phase(XinE, offs_e, nbr_e, rinE, E, row0, As, Stg[wave], wave, lane);
        conv_mfma_pool_phase(WtE, biasE, E, row0, As, pool, wave, lane, seg, outp, uni);
    }
    __syncthreads();
    if (uni) {
        float s = pool[0][tid] + pool[1][tid];
        atomicAdd(&outp[(size_t)gblk * H + tid], s);
    }
}

// ---------------- readout MLP ----------------
__global__ __launch_bounds__(128) void readout_k(const float* __restrict__ hg, const float* __restrict__ he,
                                                 const int* __restrict__ cn, const int* __restrict__ ce,
                                                 const float* __restrict__ r1w, const float* __restrict__ r1b,
                                                 const float* __restrict__ r2w, const float* __restrict__ r2b,
                                                 float* __restrict__ out) {
    const int b = blockIdx.x;
    const int j = threadIdx.x;
    const float invn = 1.f / fmaxf((float)cn[b], 1.f);
    const float inve = 1.f / fmaxf((float)ce[b], 1.f);
    float acc = r1b[j];
    for (int k = 0; k < H; ++k) acc = fmaf(hg[(size_t)b * H + k] * invn, r1w[(size_t)k * H + j], acc);
    for (int k = 0; k < H; ++k) acc = fmaf(he[(size_t)b * H + k] * inve, r1w[(size_t)(k + H) * H + j], acc);
    float s = acc / (1.f + expf(-acc));
    __shared__ float red[128];
    red[j] = s * r2w[j];
    __syncthreads();
    for (int off = 64; off > 0; off >>= 1) {
        if (j < off) red[j] += red[j + off];
        __syncthreads();
    }
    if (j == 0) out[b] = red[0] + r2b[0];
}

// diagnostic
__global__ void report_k(float* out, int n, float val) {
    int i = blockIdx.x * 64 + threadIdx.x;
    if (i < n) out[i] = val;
}

extern "C" void kernel_launch(void* const* d_in, const int* in_sizes, int n_in,
                              void* d_out, int out_size, void* d_ws, size_t ws_size,
                              hipStream_t stream) {
    const int* z          = (const int*)d_in[0];
    const float* d        = (const float*)d_in[1];
    const int* src        = (const int*)d_in[2];
    const int* dst        = (const int*)d_in[3];
    const int* lsrc       = (const int*)d_in[4];
    const int* ldst       = (const int*)d_in[5];
    const int* node_graph = (const int*)d_in[6];
    const int* edge_graph = (const int*)d_in[7];
    const float* emb      = (const float*)d_in[8];
    const float* epw      = (const float*)d_in[9];
    const float* epb      = (const float*)d_in[10];
    const float* gW       = (const float*)d_in[11];
    const float* gb       = (const float*)d_in[12];
    const float* lgW      = (const float*)d_in[13];
    const float* lgb      = (const float*)d_in[14];
    const float* r1w      = (const float*)d_in[15];
    const float* r1b      = (const float*)d_in[16];
    const float* r2w      = (const float*)d_in[17];
    const float* r2b      = (const float*)d_in[18];

    const int N  = in_sizes[0];
    const int E  = in_sizes[2];
    const int E2 = in_sizes[4];
    const int B  = out_size;
    const int L  = 3;
    float* out = (float*)d_out;
    char* ws = (char*)d_ws;

    // ---- workspace (~232 MB; budget 268 MB) ----
    size_t off = 0;
    auto al = [&](size_t b) -> char* { char* q = ws + off; off += (b + 255) & ~(size_t)255; return q; };
    u8*  featEA = (u8*)al((size_t)E * H);
    u8*  featEB = (u8*)al((size_t)E * H);
    u8*  featNA = (u8*)al((size_t)N * H);
    u8*  featNB = (u8*)al((size_t)N * H);
    f16* wt    = (f16*)al((size_t)2 * L * H * H * 2);
    float* uv  = (float*)al((size_t)2 * H * 4);
    float* ron = (float*)al((size_t)N * 4);
    float* rin = (float*)al((size_t)N * 4);
    float* roe = (float*)al((size_t)E * 4);
    float* rie = (float*)al((size_t)E * 4);
    float2* pairE = (float2*)al((size_t)E * 8);
    // cnts + pools in ONE allocation so one memset covers both
    size_t cntCount = (size_t)2 * N + 2 * E + 2 * B;
    size_t cntBytes = cntCount * 4;
    size_t poolsOff = (cntBytes + 255) & ~(size_t)255;
    char* zblock = al(poolsOff + (size_t)2 * B * H * 4);
    int* cnts = (int*)zblock;
    float* pools = (float*)(zblock + poolsOff);
    int* con = cnts; int* cin_ = con + N; int* coe = cin_ + N; int* cie = coe + E;
    int* cntn = cie + E; int* cnte = cntn + B;
    float* hg = pools;
    float* he = pools + (size_t)B * H;
    int* offs_n = (int*)al(((size_t)N + 1) * 4);
    int* cur_n  = (int*)al((size_t)N * 4);
    int* offs_e = (int*)al(((size_t)E + 1) * 4);
    int* cur_e  = (int*)al((size_t)E * 4);
    uint2* nbr_n = (uint2*)al((size_t)E * 8);
    uint2* nbr_e = (uint2*)al((size_t)E2 * 8);
    float2* pslot = (float2*)al((size_t)E2 * 8);
    int nbN = cdiv(N, 256), nbE = cdiv(E, 256);
    int* bsum   = (int*)al(((size_t)nbN + nbE + 2) * 4);

    if (off > ws_size) {
        report_k<<<cdiv(B, 64), 64, 0, stream>>>(out, B, (float)(ws_size >> 20));
        return;
    }

    // one memset: degree counters + (cntn/cnte, overwritten later, harmless) + pools
    hipMemsetAsync(zblock, 0, poolsOff + (size_t)2 * B * H * 4, stream);

    // setup1: prep_w ++ hist ++ seg bounds ++ uv
    const int nbPW = 2 * L * 64;
    const int nbHI = cdiv((long long)E + E2, 256);
    setup1_k<<<nbPW + nbHI + 3, 256, 0, stream>>>(gW, lgW, wt, L, nbPW,
                                                  src, dst, lsrc, ldst, con, cin_, coe, cie,
                                                  E, E2, nbHI, node_graph, N, edge_graph, B, cntn, cnte,
                                                  epw, epb, uv);

    // setup2: rs(+pairE) ++ block scans
    const int nbRS = cdiv((long long)2 * N + 2 * E, 256);
    setup2_k<<<nbRS + nbN + nbE, 256, 0, stream>>>(con, cin_, coe, cie, ron, rin, roe, rie,
                                                   d, pairE, N, E, nbRS, offs_n, nbN, offs_e, bsum);
    scan_bsum2_k<<<1, 256, 0, stream>>>(bsum, nbN, nbE);

    // setup3: scan add ++ node feature init
    const int nbIN = cdiv((long long)N * 32, 256);
    setup3_k<<<nbN + nbE + nbIN, 256, 0, stream>>>(offs_n, cur_n, N, nbN, E,
                                                   offs_e, cur_e, E2, nbE, bsum, z, emb, ron, featNA);

    // CSR fill (both graphs; line slots also get pairE copy)
    fill2_k<<<cdiv((long long)E + E2, 256), 256, 0, stream>>>(src, dst, lsrc, ldst, cur_n, cur_e,
                                                              nbr_n, nbr_e, pairE, pslot, E, E2);

    const int nbCN = cdiv(N, 32), nbCE = cdiv(E, 32);

    // layer 0: node standard ++ line rank-2 collapse
    conv2_l0_k<<<nbCN + nbCE, 128, 0, stream>>>(
        featNA, featNB, offs_n, nbr_n, rin, wt, gb, ron, N, nbCN,
        featEB, offs_e, pslot, rie, uv, lgb, roe, E);

    // layer 1 (middle)
    conv2_k<<<nbCN + nbCE, 128, 0, stream>>>(
        featNB, featNA, offs_n, nbr_n, rin, wt + (size_t)1 * H * H, gb + (size_t)1 * H, ron, N, nbCN,
        featEB, featEA, offs_e, nbr_e, rie, wt + (size_t)(L + 1) * H * H, lgb + (size_t)1 * H, roe, E);

    // layer 2 (final): conv + fused register pooling
    conv2_last_k<<<nbCN + nbCE, 128, 0, stream>>>(
        featNA, offs_n, nbr_n, rin, wt + (size_t)2 * H * H, gb + (size_t)2 * H, N, nbCN, node_graph, hg,
        featEA, offs_e, nbr_e, rie, wt + (size_t)(L + 2) * H * H, lgb + (size_t)2 * H, E, edge_graph, he);

    readout_k<<<B, 128, 0, stream>>>(hg, he, cntn, cnte, r1w, r1b, r2w, r2b, out);
}

// Round 14
// 970.271 us; speedup vs baseline: 1.0722x; 1.0722x over previous
//
#include <hip/hip_runtime.h>
#include <math.h>

#define H 128
typedef unsigned short u16;
typedef unsigned char u8;
typedef unsigned int u32;
typedef _Float16 f16;
typedef f16 f16x8 __attribute__((ext_vector_type(8)));
typedef float f32x4 __attribute__((ext_vector_type(4)));
typedef float f32x2 __attribute__((ext_vector_type(2)));

typedef __attribute__((address_space(1))) const void gas_void;
typedef __attribute__((address_space(3))) void las_void;

#if __has_builtin(__builtin_amdgcn_cvt_pk_fp8_f32)
#define HW8 1
#else
#define HW8 0
#endif

#define SSTRIDE 144   // fp8 staging row stride

static inline int cdiv(long long a, long long b) { return (int)((a + b - 1) / b); }

// Per-segment XCD-chunked swizzle (balanced: 1/8 of node + 1/8 of line per XCD).
__device__ __forceinline__ int swz_seg(int orig, int n) {
    int q = n >> 3, r = n & 7;
    int x = orig & 7;
    int base = (x < r) ? x * (q + 1) : r * (q + 1) + (x - r) * q;
    return base + (orig >> 3);
}
__device__ __forceinline__ int conv_bid(int orig, int nbCN, int nwg) {
    return (orig < nbCN) ? swz_seg(orig, nbCN)
                         : nbCN + swz_seg(orig - nbCN, nwg - nbCN);
}

// ---------------- fp8 e4m3fn software codec (fallback) ----------------
struct F8 {
    static __device__ inline float dec(u8 v) {
        int e = (v >> 3) & 15, m = v & 7;
        float f = (e == 0) ? (float)m * 0.001953125f : ldexpf(1.f + 0.125f * (float)m, e - 7);
        return (v & 0x80) ? -f : f;
    }
    static __device__ inline u8 enc(float x) {
        u8 s = (u8)((__float_as_uint(x) >> 24) & 0x80);
        float ax = fabsf(x);
        if (!(ax < 448.f)) return s | 0x7E;
        if (ax < 0.015625f) {
            int m = (int)rintf(ax * 512.f);
            if (m >= 8) return s | 0x08;
            return s | (u8)m;
        }
        int e; float fr = frexpf(ax, &e);
        int E = e - 1;
        int m = (int)rintf(fr * 16.f - 8.f);
        if (m == 8) { m = 0; ++E; }
        if (E > 8) return s | 0x7E;
        return s | (u8)(((E + 7) << 3) | m);
    }
};

static __device__ inline u32 enc4(float x0, float x1, float x2, float x3) {
#if HW8
    u32 w = __builtin_amdgcn_cvt_pk_fp8_f32(x0, x1, 0, false);
    w = __builtin_amdgcn_cvt_pk_fp8_f32(x2, x3, w, true);
    return w;
#else
    union { u8 b[4]; u32 u; } p;
    p.b[0] = F8::enc(x0); p.b[1] = F8::enc(x1); p.b[2] = F8::enc(x2); p.b[3] = F8::enc(x3);
    return p.u;
#endif
}
static __device__ inline float4 dec4(u32 v) {
#if HW8
    f32x2 lo = __builtin_amdgcn_cvt_pk_f32_fp8(v, false);
    f32x2 hi = __builtin_amdgcn_cvt_pk_f32_fp8(v, true);
    return make_float4(lo.x, lo.y, hi.x, hi.y);
#else
    union { u32 u; u8 b[4]; } c; c.u = v;
    return make_float4(F8::dec(c.b[0]), F8::dec(c.b[1]), F8::dec(c.b[2]), F8::dec(c.b[3]));
#endif
}

// ---------------- setup1: prep_w ++ hist_all ++ seg2 ++ uv precompute, one dispatch ----------------
__global__ __launch_bounds__(256) void setup1_k(
    const float* __restrict__ gW, const float* __restrict__ lgW, f16* __restrict__ wt, int L, int nbPW,
    const int* __restrict__ src, const int* __restrict__ dst,
    const int* __restrict__ lsrc, const int* __restrict__ ldst,
    int* __restrict__ con, int* __restrict__ cin, int* __restrict__ coe, int* __restrict__ cie,
    int E, int E2, int nbHI,
    const int* __restrict__ node_graph, int N, const int* __restrict__ edge_graph,
    int B, int* __restrict__ cntn, int* __restrict__ cnte,
    const float* __restrict__ epw, const float* __restrict__ epb, float* __restrict__ uv) {
    int blk = blockIdx.x;
    if (blk < nbPW) {                       // weight prep
        int mat = blk >> 6;
        int idx = (blk & 63) * 256 + threadIdx.x;
        int k = idx >> 7, n = idx & 127;
        const float* W = (mat < L) ? gW + (size_t)mat * H * H : lgW + (size_t)(mat - L) * H * H;
        wt[(size_t)mat * H * H + (size_t)n * H + k] = (f16)W[(size_t)k * H + n];
        return;
    }
    blk -= nbPW;
    if (blk < nbHI) {                       // degree histograms
        int i = blk * 256 + threadIdx.x;
        if (i < E) {
            atomicAdd(&con[src[i]], 1);
            atomicAdd(&cin[dst[i]], 1);
        } else if (i < E + E2) {
            int j = i - E;
            atomicAdd(&coe[lsrc[j]], 1);
            atomicAdd(&cie[ldst[j]], 1);
        }
        return;
    }
    blk -= nbHI;                            // seg bounds (2 blocks)
    if (blk < 2) {
        const int* seg = blk ? edge_graph : node_graph;
        int n = blk ? E : N;
        int* cnt = blk ? cnte : cntn;
        __shared__ int bound[129];
        int b = threadIdx.x;
        if (b <= B) {
            int lo = 0, hi = n;
            while (lo < hi) {
                int mid = (lo + hi) >> 1;
                if (seg[mid] < b) lo = mid + 1; else hi = mid;
            }
            bound[b] = lo;
        }
        __syncthreads();
        if (b < B) cnt[b] = bound[b + 1] - bound[b];
        return;
    }
    // last block: uv precompute  u = epw @ lgW[0],  v = epb @ lgW[0]
    {
        int n = threadIdx.x;
        if (n < H) {
            float su = 0.f, sv = 0.f;
            for (int k = 0; k < H; ++k) {
                float w = lgW[(size_t)k * H + n];
                su = fmaf(epw[k], w, su);
                sv = fmaf(epb[k], w, sv);
            }
            uv[n] = su;
            uv[n + H] = sv;
        }
    }
}

// ---------------- setup2: rs_all(+pairE) ++ scan_block2, one dispatch ----------------
__global__ __launch_bounds__(256) void setup2_k(
    const int* __restrict__ con, const int* __restrict__ cin,
    const int* __restrict__ coe, const int* __restrict__ cie,
    float* __restrict__ ron, float* __restrict__ rin,
    float* __restrict__ roe, float* __restrict__ rie,
    const float* __restrict__ d, float2* __restrict__ pairE, int N, int E, int nbRS,
    int* __restrict__ offs_n, int nbN, int* __restrict__ offs_e, int* __restrict__ bsum) {
    int blk = blockIdx.x;
    if (blk < nbRS) {                       // rs + pairE
        int i = blk * 256 + threadIdx.x;
        if (i < N) { int v = con[i]; ron[i] = rsqrtf((float)(v < 1 ? 1 : v)); }
        else if (i < 2 * N) { int n = i - N; int v = cin[n]; rin[n] = rsqrtf((float)(v < 1 ? 1 : v)); }
        else if (i < 2 * N + E) {
            int n = i - 2 * N; int v = coe[n];
            float r = rsqrtf((float)(v < 1 ? 1 : v));
            roe[n] = r;
            pairE[n] = make_float2(r * d[n], r);
        } else if (i < 2 * N + 2 * E) {
            int n = i - 2 * N - E; int v = cie[n]; rie[n] = rsqrtf((float)(v < 1 ? 1 : v));
        }
        return;
    }
    blk -= nbRS;                            // block scans (nbN for cin->offs_n, rest cie->offs_e)
    {
        __shared__ int sh[256];
        const int* in; int* out; int n; int gid;
        if (blk < nbN) { in = cin; out = offs_n; n = N; gid = blk * 256 + threadIdx.x; }
        else { in = cie; out = offs_e; n = E; gid = (blk - nbN) * 256 + threadIdx.x; }
        int v = (gid < n) ? in[gid] : 0;
        sh[threadIdx.x] = v;
        __syncthreads();
        for (int off = 1; off < 256; off <<= 1) {
            int t = (threadIdx.x >= off) ? sh[threadIdx.x - off] : 0;
            __syncthreads();
            sh[threadIdx.x] += t;
            __syncthreads();
        }
        if (gid < n) out[gid] = sh[threadIdx.x] - v;
        if (threadIdx.x == 255) bsum[blk] = sh[255];
    }
}

__global__ __launch_bounds__(256) void scan_bsum2_k(int* __restrict__ bsum, int nbA, int nbB) {
    __shared__ int sh[256];
    __shared__ int carry;
#pragma unroll 1
    for (int part = 0; part < 2; ++part) {
        int base0 = part ? nbA : 0;
        int nb = part ? nbB : nbA;
        if (threadIdx.x == 0) carry = 0;
        __syncthreads();
        for (int base = 0; base < nb; base += 256) {
            int i = base + threadIdx.x;
            int v = (i < nb) ? bsum[base0 + i] : 0;
            sh[threadIdx.x] = v;
            __syncthreads();
            for (int off = 1; off < 256; off <<= 1) {
                int t = (threadIdx.x >= off) ? sh[threadIdx.x - off] : 0;
                __syncthreads();
                sh[threadIdx.x] += t;
                __syncthreads();
            }
            if (i < nb) bsum[base0 + i] = sh[threadIdx.x] - v + carry;
            __syncthreads();
            if (threadIdx.x == 0) carry += sh[255];
            __syncthreads();
        }
    }
}

// ---------------- setup3: scan_add2 ++ init_node, one dispatch ----------------
__global__ __launch_bounds__(256) void setup3_k(
    int* __restrict__ offs_n, int* __restrict__ cur_n, int N, int nbN, int E,
    int* __restrict__ offs_e, int* __restrict__ cur_e, int E2, int nbE,
    const int* __restrict__ bsum,
    const int* __restrict__ z, const float* __restrict__ emb,
    const float* __restrict__ ron, u8* __restrict__ featN) {
    int blk = blockIdx.x;
    int nbSA = nbN + nbE;
    if (blk < nbSA) {                       // scan add (offs += bsum; cursor init; tail nnz)
        int* offs; int* curp; int n; int gid; int nnz;
        if (blk < nbN) { offs = offs_n; curp = cur_n; n = N; gid = blk * 256 + threadIdx.x; nnz = E; }
        else { offs = offs_e; curp = cur_e; n = E; gid = (blk - nbN) * 256 + threadIdx.x; nnz = E2; }
        if (gid < n) {
            int v = offs[gid] + bsum[blk];
            offs[gid] = v;
            curp[gid] = v;
        }
        if (gid == 0) offs[n] = nnz;
        return;
    }
    blk -= nbSA;                            // node feature init (fp8, pre-scaled by ron)
    {
        int idx = blk * 256 + threadIdx.x;
        if (idx >= N * 32) return;
        int n = idx >> 5, c4 = (idx & 31) << 2;
        float sc = ron[n];
        const float4 v = *(const float4*)(emb + (size_t)z[n] * H + c4);
        *(u32*)(featN + (size_t)n * H + c4) = enc4(v.x * sc, v.y * sc, v.z * sc, v.w * sc);
    }
}

// ---------------- CSR fill (both graphs): slot gets (src, dst) pair; line slots also pairE ----------------
__global__ __launch_bounds__(256) void fill2_k(const int* __restrict__ src, const int* __restrict__ dst,
                                               const int* __restrict__ lsrc, const int* __restrict__ ldst,
                                               int* __restrict__ cur_n, int* __restrict__ cur_e,
                                               uint2* __restrict__ nbr_n, uint2* __restrict__ nbr_e,
                                               const float2* __restrict__ pairE, float2* __restrict__ pslot,
                                               int E, int E2) {
    int i = blockIdx.x * 256 + threadIdx.x;
    if (i < E) {
        int dd = dst[i];
        int p = atomicAdd(&cur_n[dd], 1);
        nbr_n[p] = make_uint2((u32)src[i], (u32)dd);
    } else if (i < E + E2) {
        int j = i - E;
        int ls = lsrc[j];
        int dd = ldst[j];
        int p = atomicAdd(&cur_e[dd], 1);
        nbr_e[p] = make_uint2((u32)ls, (u32)dd);
        pslot[p] = pairE[ls];               // CSR-ordered copy: l0 gather becomes sequential
    }
}

// ---------------- gather: feature rows via global_load_lds ring-2, vmcnt-gated ----------------
// Best measured config (r12: conv2_k 222us). 16-lane-group parallel processing;
// feature loads via a 2-deep global_load_lds ring gated by asm vmcnt(2).
__device__ __forceinline__ void gather_phase(
    const u8* __restrict__ Xin,
    const int* __restrict__ offs, const uint2* __restrict__ nbr2,
    const float* __restrict__ rs_in, int M,
    int row0, f16 (*As)[136], u8* __restrict__ featRing, int wave, int lane) {
    const int rowbase = row0 + wave * 16;
    {
        uint2* zp = (uint2*)&As[wave * 16][0];
#pragma unroll
        for (int i = 0; i < 9; ++i) {
            int o = lane + i * 64;
            if (o < 544) zp[o] = make_uint2(0u, 0u);
        }
    }
    const int gl = lane >> 4;
    const int ln = lane & 15;
    const int rbase4 = rowbase + gl * 4;
    const int jbeg = offs[min(rbase4, M)];
    const int jend = offs[min(rbase4 + 4, M)];
    if (jbeg >= jend) return;   // empty group: lanes exec-masked off; its stale LDS never read
    const int mrow = M - 1;
    const float rsr0 = rs_in[min(rbase4 + 0, mrow)];
    const float rsr1 = rs_in[min(rbase4 + 1, mrow)];
    const float rsr2 = rs_in[min(rbase4 + 2, mrow)];
    const float rsr3 = rs_in[min(rbase4 + 3, mrow)];

    float a0 = 0.f, a1 = 0.f, a2 = 0.f, a3 = 0.f, a4 = 0.f, a5 = 0.f, a6 = 0.f, a7 = 0.f;
    int curdst = -1;

#define FLUSH_ROW()                                                              \
    do {                                                                         \
        const int dd_ = curdst - rbase4;                                         \
        const float ri_ = dd_ == 0 ? rsr0 : (dd_ == 1 ? rsr1 : (dd_ == 2 ? rsr2 : rsr3)); \
        f16x8 o_;                                                                \
        o_[0] = (f16)(a0 * ri_); o_[1] = (f16)(a1 * ri_);                        \
        o_[2] = (f16)(a2 * ri_); o_[3] = (f16)(a3 * ri_);                        \
        o_[4] = (f16)(a4 * ri_); o_[5] = (f16)(a5 * ri_);                        \
        o_[6] = (f16)(a6 * ri_); o_[7] = (f16)(a7 * ri_);                        \
        *(f16x8*)&As[curdst - row0][ln << 3] = o_;                               \
    } while (0)

    // HW writes lane i at ldsbase + i*16; lane = gl*16 + sub*8 + (ln&7):
    // edge (pairbase+sub) row lands at gl*256 + sub*128. Static select for sub
    // (rule #20: no runtime-indexed register arrays).
    const int sub = (lane >> 3) & 1;
    const size_t c16 = (size_t)(lane & 7) << 4;
#define STAGE(eX, rg) do {                                                        \
        u32 rxa_ = sub ? eX[1].x : eX[0].x;                                       \
        u32 rxb_ = sub ? eX[3].x : eX[2].x;                                       \
        __builtin_amdgcn_global_load_lds(                                         \
            (gas_void*)(Xin + ((size_t)rxa_ << 7) + c16),                         \
            (las_void*)(featRing + (rg) * 2048), 16, 0, 0);                       \
        __builtin_amdgcn_global_load_lds(                                         \
            (gas_void*)(Xin + ((size_t)rxb_ << 7) + c16),                         \
            (las_void*)(featRing + (rg) * 2048 + 1024), 16, 0, 0);                \
    } while (0)

    uint2 eA[4], eB[4];
#pragma unroll
    for (int k = 0; k < 4; ++k) eA[k] = nbr2[min(jbeg + k, jend - 1)];
    STAGE(eA, 0);
#pragma unroll
    for (int k = 0; k < 4; ++k) eB[k] = nbr2[min(jbeg + 4 + k, jend - 1)];
    int ring = 0;
    for (int jc = jbeg; ; ) {
        const bool more = (jc + 4 < jend);
        if (more) {
            STAGE(eB, ring ^ 1);
            asm volatile("s_waitcnt vmcnt(2)" ::: "memory");  // all but the 2 new: cur ring resident
        } else {
            asm volatile("s_waitcnt vmcnt(0)" ::: "memory");
        }
        __builtin_amdgcn_sched_barrier(0);
        const u8* fb = featRing + ring * 2048 + gl * 256;
#pragma unroll
        for (int k = 0; k < 4; ++k) {
            if (jc + k < jend) {
                const int dk = (int)eA[k].y;
                if (dk != curdst) {
                    if (curdst >= 0) {
                        FLUSH_ROW();
                        a0 = a1 = a2 = a3 = a4 = a5 = a6 = a7 = 0.f;
                    }
                    curdst = dk;
                }
                uint2 fv = *(const uint2*)(fb + (k >> 1) * 1024 + (k & 1) * 128 + (ln << 3));
                float4 lo = dec4(fv.x);
                float4 hi = dec4(fv.y);
                a0 += lo.x; a1 += lo.y; a2 += lo.z; a3 += lo.w;
                a4 += hi.x; a5 += hi.y; a6 += hi.z; a7 += hi.w;
            }
        }
        jc += 4;
        if (jc >= jend) break;
#pragma unroll
        for (int k = 0; k < 4; ++k) eA[k] = eB[k];
        if (jc + 4 < jend) {
#pragma unroll
            for (int k = 0; k < 4; ++k) eB[k] = nbr2[min(jc + 4 + k, jend - 1)];
        }
        ring ^= 1;
    }
    FLUSH_ROW();
#undef STAGE
#undef FLUSH_ROW
}

// ---------------- MFMA phase: LDS-staged fp8 output; optional full-line global store ----------------
template <bool STORE>
__device__ __forceinline__ void conv_mfma_phase(
    u8* __restrict__ Xout, const f16* __restrict__ Wt, const float* __restrict__ bias,
    const float* __restrict__ scale_out, int M, int row0, f16 (*As)[136], int wave, int lane) {
    const int rowbase = row0 + wave * 16;
    if (rowbase >= M) return;
    const int l15 = lane & 15;
    const int quad = lane >> 4;

    f16x8 a[4];
#pragma unroll
    for (int kt = 0; kt < 4; ++kt)
        a[kt] = *(const f16x8*)&As[wave * 16 + l15][kt * 32 + quad * 8];

    float rsc[4];
#pragma unroll
    for (int r = 0; r < 4; ++r) {
        int gr = rowbase + quad * 4 + r;
        rsc[r] = (scale_out && gr < M) ? scale_out[gr] : 1.f;
    }

    u8* stage = (u8*)&As[wave * 16][0];

#pragma unroll
    for (int n0 = 0; n0 < 8; ++n0) {
        f32x4 acc = {0.f, 0.f, 0.f, 0.f};
        const f16* bp = Wt + (size_t)(n0 * 16 + l15) * H + quad * 8;
#pragma unroll
        for (int kt = 0; kt < 4; ++kt) {
            f16x8 b = *(const f16x8*)(bp + kt * 32);
            acc = __builtin_amdgcn_mfma_f32_16x16x32_f16(a[kt], b, acc, 0, 0, 0);
        }
        int col = n0 * 16 + l15;
        float bv = bias[col];
        float o[4];
#pragma unroll
        for (int r = 0; r < 4; ++r) o[r] = fmaxf(acc[r] + bv, 0.f) * rsc[r];
        u32 w = enc4(o[0], o[1], o[2], o[3]);
#pragma unroll
        for (int r = 0; r < 4; ++r) stage[(quad * 4 + r) * SSTRIDE + col] = (u8)(w >> (8 * r));
    }
    if (STORE) {
        const int lr = lane >> 2;
        const int lc = (lane & 3) * 32;
        int gr = rowbase + lr;
        if (gr < M) {
            uint4 v0 = *(const uint4*)&stage[lr * SSTRIDE + lc];
            uint4 v1 = *(const uint4*)&stage[lr * SSTRIDE + lc + 16];
            *(uint4*)(Xout + (size_t)gr * H + lc) = v0;
            *(uint4*)(Xout + (size_t)gr * H + lc + 16) = v1;
        }
    }
}

// ---------------- MFMA + register-space pooling (last layer; no fp8 stage) ----------------
__device__ __forceinline__ void conv_mfma_pool_phase(
    const f16* __restrict__ Wt, const float* __restrict__ bias, int M, int row0,
    f16 (*As)[136], float (*pool)[128], int wave, int lane,
    const int* __restrict__ seg, float* __restrict__ outp, bool uni) {
    const int rowbase = row0 + wave * 16;
    if (rowbase >= M) return;       // pool[wave] stays zeroed
    const int l15 = lane & 15;
    const int quad = lane >> 4;

    f16x8 a[4];
#pragma unroll
    for (int kt = 0; kt < 4; ++kt)
        a[kt] = *(const f16x8*)&As[wave * 16 + l15][kt * 32 + quad * 8];

    const int gr0 = rowbase + quad * 4;
    const int remM = M - gr0;       // rows valid iff r < remM
    int g0 = -1, g1 = -1, g2 = -1, g3 = -1;
    if (!uni) {                     // block-uniform branch
        g0 = (0 < remM) ? seg[gr0 + 0] : -1;
        g1 = (1 < remM) ? seg[gr0 + 1] : -1;
        g2 = (2 < remM) ? seg[gr0 + 2] : -1;
        g3 = (3 < remM) ? seg[gr0 + 3] : -1;
    }

#pragma unroll
    for (int n0 = 0; n0 < 8; ++n0) {
        f32x4 acc = {0.f, 0.f, 0.f, 0.f};
        const f16* bp = Wt + (size_t)(n0 * 16 + l15) * H + quad * 8;
#pragma unroll
        for (int kt = 0; kt < 4; ++kt) {
            f16x8 b = *(const f16x8*)(bp + kt * 32);
            acc = __builtin_amdgcn_mfma_f32_16x16x32_f16(a[kt], b, acc, 0, 0, 0);
        }
        const int col = n0 * 16 + l15;
        const float bv = bias[col];
        const float o0 = (0 < remM) ? fmaxf(acc[0] + bv, 0.f) : 0.f;
        const float o1 = (1 < remM) ? fmaxf(acc[1] + bv, 0.f) : 0.f;
        const float o2 = (2 < remM) ? fmaxf(acc[2] + bv, 0.f) : 0.f;
        const float o3 = (3 < remM) ? fmaxf(acc[3] + bv, 0.f) : 0.f;
        if (uni) {
            float s = (o0 + o1) + (o2 + o3);
            s += __shfl_xor(s, 16);
            s += __shfl_xor(s, 32);
            if (quad == 0) pool[wave][col] = s;   // cols unique per wave: plain store
        } else {
            // rare boundary block: per-lane run-flush to global
            float ac = o0; int gc = g0;
            if (g1 == gc) ac += o1; else { if (gc >= 0) atomicAdd(&outp[(size_t)gc * H + col], ac); gc = g1; ac = o1; }
            if (g2 == gc) ac += o2; else { if (gc >= 0) atomicAdd(&outp[(size_t)gc * H + col], ac); gc = g2; ac = o2; }
            if (g3 == gc) ac += o3; else { if (gc >= 0) atomicAdd(&outp[(size_t)gc * H + col], ac); gc = g3; ac = o3; }
            if (gc >= 0) atomicAdd(&outp[(size_t)gc * H + col], ac);
        }
    }
}

template <bool STORE>
__device__ __forceinline__ void conv_wave(
    const u8* __restrict__ Xin, u8* __restrict__ Xout,
    const int* __restrict__ offs, const uint2* __restrict__ nbr2,
    const float* __restrict__ rs_in, const f16* __restrict__ Wt,
    const float* __restrict__ bias, const float* __restrict__ scale_out, int M,
    int row0, f16 (*As)[136], u8* __restrict__ featRing, int wave, int lane) {
    gather_phase(Xin, offs, nbr2, rs_in, M, row0, As, featRing, wave, lane);
    // no __syncthreads: As slice + featRing are wave-private
    conv_mfma_phase<STORE>(Xout, Wt, bias, scale_out, M, row0, As, wave, lane);
}

// ---------------- layer-0 line conv wave: rank-2 algebraic collapse, no LDS/MFMA ----------------
// e_row = sd*epw + sw*epb  =>  out = relu(sd*(epw@W) + sw*(epb@W) + b) * scale
__device__ __forceinline__ void conv_wave_l0e(
    u8* __restrict__ Xout, const int* __restrict__ offs,
    const float2* __restrict__ pslot, const float* __restrict__ rs_in,
    const float* __restrict__ uv, const float* __restrict__ bias,
    const float* __restrict__ scale_out, int E,
    int row0, int wave, int lane) {
    const int rowbase = row0 + wave * 16;
    const int r = lane >> 2;
    const int t = lane & 3;
    const int growu = rowbase + r;
    const int grow = min(growu, E - 1);
    const int jb = offs[grow];
    const int je = offs[grow + 1];
    float sd = 0.f, sw = 0.f;
    for (int j = jb + t; j < je; j += 4) {
        float2 p = pslot[j];                 // sequential in CSR order: 1-level chain
        sd += p.x; sw += p.y;
    }
    sd += __shfl_xor(sd, 1); sw += __shfl_xor(sw, 1);
    sd += __shfl_xor(sd, 2); sw += __shfl_xor(sw, 2);
    if (growu >= E) return;
    const float ri = rs_in[growu];
    const float so = scale_out[growu];
    sd *= ri; sw *= ri;
    const int c0 = t * 32;
    u32 wbuf[8];
#pragma unroll
    for (int c4 = 0; c4 < 8; ++c4) {
        const int c = c0 + c4 * 4;
        const float4 ua = *(const float4*)(uv + c);
        const float4 va = *(const float4*)(uv + H + c);
        const float4 ba = *(const float4*)(bias + c);
        const float o0 = fmaxf(fmaf(sd, ua.x, fmaf(sw, va.x, ba.x)), 0.f) * so;
        const float o1 = fmaxf(fmaf(sd, ua.y, fmaf(sw, va.y, ba.y)), 0.f) * so;
        const float o2 = fmaxf(fmaf(sd, ua.z, fmaf(sw, va.z, ba.z)), 0.f) * so;
        const float o3 = fmaxf(fmaf(sd, ua.w, fmaf(sw, va.w, ba.w)), 0.f) * so;
        wbuf[c4] = enc4(o0, o1, o2, o3);
    }
    *(uint4*)(Xout + (size_t)growu * H + c0) = *(uint4*)&wbuf[0];
    *(uint4*)(Xout + (size_t)growu * H + c0 + 16) = *(uint4*)&wbuf[4];
}

// ---------------- combined conv (middle layer): 128t/2-wave blocks + feature DMA ring ----------------
// (128, 4): budget 64 (256-reg-pool model, measured r7-r9). Measured r12: VGPR 52,
// no spill; LDS/block = As 8704 + Stg 8192 = 16896.
__global__ __launch_bounds__(128, 4) void conv2_k(
    const u8* __restrict__ XinN, u8* __restrict__ XoutN,
    const int* __restrict__ offs_n, const uint2* __restrict__ nbr_n,
    const float* __restrict__ rinN, const f16* __restrict__ WtN,
    const float* __restrict__ biasN, const float* __restrict__ scaleN, int N, int nbCN,
    const u8* __restrict__ XinE, u8* __restrict__ XoutE,
    const int* __restrict__ offs_e, const uint2* __restrict__ nbr_e,
    const float* __restrict__ rinE, const f16* __restrict__ WtE,
    const float* __restrict__ biasE, const float* __restrict__ scaleE, int E) {
    __shared__ f16 As[32][136];
    __shared__ u8 Stg[2][4096];
    const int tid = threadIdx.x;
    const int wave = tid >> 6;
    const int lane = tid & 63;
    const int bid = conv_bid((int)blockIdx.x, nbCN, (int)gridDim.x);
    if (bid < nbCN) {
        conv_wave<true>(XinN, XoutN, offs_n, nbr_n, rinN, WtN, biasN, scaleN, N,
                        bid * 32, As, Stg[wave], wave, lane);
    } else {
        conv_wave<true>(XinE, XoutE, offs_e, nbr_e, rinE, WtE, biasE, scaleE, E,
                        (bid - nbCN) * 32, As, Stg[wave], wave, lane);
    }
}

// ---------------- combined conv layer 0: node standard ++ line rank-2 collapse ----------------
__global__ __launch_bounds__(128, 4) void conv2_l0_k(
    const u8* __restrict__ XinN, u8* __restrict__ XoutN,
    const int* __restrict__ offs_n, const uint2* __restrict__ nbr_n,
    const float* __restrict__ rinN, const f16* __restrict__ WtN,
    const float* __restrict__ biasN, const float* __restrict__ scaleN, int N, int nbCN,
    u8* __restrict__ XoutE,
    const int* __restrict__ offs_e, const float2* __restrict__ pslot,
    const float* __restrict__ rinE, const float* __restrict__ uv,
    const float* __restrict__ biasE, const float* __restrict__ scaleE, int E) {
    __shared__ f16 As[32][136];
    __shared__ u8 Stg[2][4096];
    const int tid = threadIdx.x;
    const int wave = tid >> 6;
    const int lane = tid & 63;
    const int bid = conv_bid((int)blockIdx.x, nbCN, (int)gridDim.x);
    if (bid < nbCN) {
        conv_wave<true>(XinN, XoutN, offs_n, nbr_n, rinN, WtN, biasN, scaleN, N,
                        bid * 32, As, Stg[wave], wave, lane);
    } else {
        conv_wave_l0e(XoutE, offs_e, pslot, rinE, uv, biasE, scaleE, E,
                      (bid - nbCN) * 32, wave, lane);
    }
}

// ---------------- final conv layer: conv + register-space fused block pooling (32 rows) ----------------
__global__ __launch_bounds__(128, 4) void conv2_last_k(
    const u8* __restrict__ XinN,
    const int* __restrict__ offs_n, const uint2* __restrict__ nbr_n,
    const float* __restrict__ rinN, const f16* __restrict__ WtN,
    const float* __restrict__ biasN, int N, int nbCN,
    const int* __restrict__ node_graph, float* __restrict__ hg,
    const u8* __restrict__ XinE,
    const int* __restrict__ offs_e, const uint2* __restrict__ nbr_e,
    const float* __restrict__ rinE, const f16* __restrict__ WtE,
    const float* __restrict__ biasE, int E,
    const int* __restrict__ edge_graph, float* __restrict__ he) {
    __shared__ f16 As[32][136];
    __shared__ u8 Stg[2][4096];
    __shared__ float pool[2][128];
    const int tid = threadIdx.x;
    const int wave = tid >> 6;
    const int lane = tid & 63;
    const int bid = conv_bid((int)blockIdx.x, nbCN, (int)gridDim.x);
    const bool isN = bid < nbCN;
    const int row0 = (isN ? bid : bid - nbCN) * 32;
    const int M = isN ? N : E;
    const int* seg = isN ? node_graph : edge_graph;
    float* outp = isN ? hg : he;

    ((float*)pool)[tid] = 0.f;
    ((float*)pool)[tid + 128] = 0.f;
    const int gblk = seg[row0];
    const bool uni = (seg[min(row0 + 31, M - 1)] == gblk);
    __syncthreads();

    if (isN) {
        gather_phase(XinN, offs_n, nbr_n, rinN, N, row0, As, Stg[wave], wave, lane);
        conv_mfma_pool_phase(WtN, biasN, N, row0, As, pool, wave, lane, seg, outp, uni);
    } else {
        gather_phase(XinE, offs_e, nbr_e, rinE, E, row0, As, Stg[wave], wave, lane);
        conv_mfma_pool_phase(WtE, biasE, E, row0, As, pool, wave, lane, seg, outp, uni);
    }
    __syncthreads();
    if (uni) {
        float s = pool[0][tid] + pool[1][tid];
        atomicAdd(&outp[(size_t)gblk * H + tid], s);
    }
}

// ---------------- readout MLP ----------------
__global__ __launch_bounds__(128) void readout_k(const float* __restrict__ hg, const float* __restrict__ he,
                                                 const int* __restrict__ cn, const int* __restrict__ ce,
                                                 const float* __restrict__ r1w, const float* __restrict__ r1b,
                                                 const float* __restrict__ r2w, const float* __restrict__ r2b,
                                                 float* __restrict__ out) {
    const int b = blockIdx.x;
    const int j = threadIdx.x;
    const float invn = 1.f / fmaxf((float)cn[b], 1.f);
    const float inve = 1.f / fmaxf((float)ce[b], 1.f);
    float acc = r1b[j];
    for (int k = 0; k < H; ++k) acc = fmaf(hg[(size_t)b * H + k] * invn, r1w[(size_t)k * H + j], acc);
    for (int k = 0; k < H; ++k) acc = fmaf(he[(size_t)b * H + k] * inve, r1w[(size_t)(k + H) * H + j], acc);
    float s = acc / (1.f + expf(-acc));
    __shared__ float red[128];
    red[j] = s * r2w[j];
    __syncthreads();
    for (int off = 64; off > 0; off >>= 1) {
        if (j < off) red[j] += red[j + off];
        __syncthreads();
    }
    if (j == 0) out[b] = red[0] + r2b[0];
}

// diagnostic
__global__ void report_k(float* out, int n, float val) {
    int i = blockIdx.x * 64 + threadIdx.x;
    if (i < n) out[i] = val;
}

extern "C" void kernel_launch(void* const* d_in, const int* in_sizes, int n_in,
                              void* d_out, int out_size, void* d_ws, size_t ws_size,
                              hipStream_t stream) {
    const int* z          = (const int*)d_in[0];
    const float* d        = (const float*)d_in[1];
    const int* src        = (const int*)d_in[2];
    const int* dst        = (const int*)d_in[3];
    const int* lsrc       = (const int*)d_in[4];
    const int* ldst       = (const int*)d_in[5];
    const int* node_graph = (const int*)d_in[6];
    const int* edge_graph = (const int*)d_in[7];
    const float* emb      = (const float*)d_in[8];
    const float* epw      = (const float*)d_in[9];
    const float* epb      = (const float*)d_in[10];
    const float* gW       = (const float*)d_in[11];
    const float* gb       = (const float*)d_in[12];
    const float* lgW      = (const float*)d_in[13];
    const float* lgb      = (const float*)d_in[14];
    const float* r1w      = (const float*)d_in[15];
    const float* r1b      = (const float*)d_in[16];
    const float* r2w      = (const float*)d_in[17];
    const float* r2b      = (const float*)d_in[18];

    const int N  = in_sizes[0];
    const int E  = in_sizes[2];
    const int E2 = in_sizes[4];
    const int B  = out_size;
    const int L  = 3;
    float* out = (float*)d_out;
    char* ws = (char*)d_ws;

    // ---- workspace (~232 MB; budget 268 MB) ----
    size_t off = 0;
    auto al = [&](size_t b) -> char* { char* q = ws + off; off += (b + 255) & ~(size_t)255; return q; };
    u8*  featEA = (u8*)al((size_t)E * H);
    u8*  featEB = (u8*)al((size_t)E * H);
    u8*  featNA = (u8*)al((size_t)N * H);
    u8*  featNB = (u8*)al((size_t)N * H);
    f16* wt    = (f16*)al((size_t)2 * L * H * H * 2);
    float* uv  = (float*)al((size_t)2 * H * 4);
    float* ron = (float*)al((size_t)N * 4);
    float* rin = (float*)al((size_t)N * 4);
    float* roe = (float*)al((size_t)E * 4);
    float* rie = (float*)al((size_t)E * 4);
    float2* pairE = (float2*)al((size_t)E * 8);
    // cnts + pools in ONE allocation so one memset covers both
    size_t cntCount = (size_t)2 * N + 2 * E + 2 * B;
    size_t cntBytes = cntCount * 4;
    size_t poolsOff = (cntBytes + 255) & ~(size_t)255;
    char* zblock = al(poolsOff + (size_t)2 * B * H * 4);
    int* cnts = (int*)zblock;
    float* pools = (float*)(zblock + poolsOff);
    int* con = cnts; int* cin_ = con + N; int* coe = cin_ + N; int* cie = coe + E;
    int* cntn = cie + E; int* cnte = cntn + B;
    float* hg = pools;
    float* he = pools + (size_t)B * H;
    int* offs_n = (int*)al(((size_t)N + 1) * 4);
    int* cur_n  = (int*)al((size_t)N * 4);
    int* offs_e = (int*)al(((size_t)E + 1) * 4);
    int* cur_e  = (int*)al((size_t)E * 4);
    uint2* nbr_n = (uint2*)al((size_t)E * 8);
    uint2* nbr_e = (uint2*)al((size_t)E2 * 8);
    float2* pslot = (float2*)al((size_t)E2 * 8);
    int nbN = cdiv(N, 256), nbE = cdiv(E, 256);
    int* bsum   = (int*)al(((size_t)nbN + nbE + 2) * 4);

    if (off > ws_size) {
        report_k<<<cdiv(B, 64), 64, 0, stream>>>(out, B, (float)(ws_size >> 20));
        return;
    }

    // one memset: degree counters + (cntn/cnte, overwritten later, harmless) + pools
    hipMemsetAsync(zblock, 0, poolsOff + (size_t)2 * B * H * 4, stream);

    // setup1: prep_w ++ hist ++ seg bounds ++ uv
    const int nbPW = 2 * L * 64;
    const int nbHI = cdiv((long long)E + E2, 256);
    setup1_k<<<nbPW + nbHI + 3, 256, 0, stream>>>(gW, lgW, wt, L, nbPW,
                                                  src, dst, lsrc, ldst, con, cin_, coe, cie,
                                                  E, E2, nbHI, node_graph, N, edge_graph, B, cntn, cnte,
                                                  epw, epb, uv);

    // setup2: rs(+pairE) ++ block scans
    const int nbRS = cdiv((long long)2 * N + 2 * E, 256);
    setup2_k<<<nbRS + nbN + nbE, 256, 0, stream>>>(con, cin_, coe, cie, ron, rin, roe, rie,
                                                   d, pairE, N, E, nbRS, offs_n, nbN, offs_e, bsum);
    scan_bsum2_k<<<1, 256, 0, stream>>>(bsum, nbN, nbE);

    // setup3: scan add ++ node feature init
    const int nbIN = cdiv((long long)N * 32, 256);
    setup3_k<<<nbN + nbE + nbIN, 256, 0, stream>>>(offs_n, cur_n, N, nbN, E,
                                                   offs_e, cur_e, E2, nbE, bsum, z, emb, ron, featNA);

    // CSR fill (both graphs; line slots also get pairE copy)
    fill2_k<<<cdiv((long long)E + E2, 256), 256, 0, stream>>>(src, dst, lsrc, ldst, cur_n, cur_e,
                                                              nbr_n, nbr_e, pairE, pslot, E, E2);

    const int nbCN = cdiv(N, 32), nbCE = cdiv(E, 32);

    // layer 0: node standard ++ line rank-2 collapse
    conv2_l0_k<<<nbCN + nbCE, 128, 0, stream>>>(
        featNA, featNB, offs_n, nbr_n, rin, wt, gb, ron, N, nbCN,
        featEB, offs_e, pslot, rie, uv, lgb, roe, E);

    // layer 1 (middle)
    conv2_k<<<nbCN + nbCE, 128, 0, stream>>>(
        featNB, featNA, offs_n, nbr_n, rin, wt + (size_t)1 * H * H, gb + (size_t)1 * H, ron, N, nbCN,
        featEB, featEA, offs_e, nbr_e, rie, wt + (size_t)(L + 1) * H * H, lgb + (size_t)1 * H, roe, E);

    // layer 2 (final): conv + fused register pooling
    conv2_last_k<<<nbCN + nbCE, 128, 0, stream>>>(
        featNA, offs_n, nbr_n, rin, wt + (size_t)2 * H * H, gb + (size_t)2 * H, N, nbCN, node_graph, hg,
        featEA, offs_e, nbr_e, rie, wt + (size_t)(L + 2) * H * H, lgb + (size_t)2 * H, E, edge_graph, he);

    readout_k<<<B, 128, 0, stream>>>(hg, he, cntn, cnte, r1w, r1b, r2w, r2b, out);
}